// Round 7
// baseline (214.961 us; speedup 1.0000x reference)
//
#include <hip/hip_runtime.h>

#define DEVINL __device__ __forceinline__

typedef float f32x2 __attribute__((ext_vector_type(2)));

DEVINL float fexp2(float x){ return __builtin_amdgcn_exp2f(x); }
DEVINL float frcp (float x){ return __builtin_amdgcn_rcpf(x); }

#define LOG2E 1.4426950408889634f

// ---------------------------------------------------------------------------
// Kernel 1: precompute per-(dir, idx, lane) input-gate table, PRE-SCALED:
//   G = { -log2e * (Wr_e·e + bih_r + bhh_r),
//         -log2e * (Wz_e·e + bih_z + bhh_z),
//         2*log2e * (Wn_e·e + bih_n), 0 }
// Plus the static part of out[b].
// ---------------------------------------------------------------------------
template<int H>
DEVINL void pre_entry(int t, const float* __restrict__ emb,
                      const float* __restrict__ Wih_f, const float* __restrict__ bih_f, const float* __restrict__ bhh_f,
                      const float* __restrict__ Wih_b, const float* __restrict__ bih_b, const float* __restrict__ bhh_b,
                      float4* __restrict__ G, int N)
{
  constexpr int E = H - 1;
  const int dir = t / (N * H);
  const int r   = t - dir * (N * H);
  const int idx = r / H;
  const int li  = r - idx * H;
  const float* Wih = dir ? Wih_b : Wih_f;
  const float* bih = dir ? bih_b : bih_f;
  const float* bhh = dir ? bhh_b : bhh_f;
  const float* e = emb + (size_t)idx * E;
  float gr = bih[li]       + bhh[li];
  float gz = bih[H + li]   + bhh[H + li];
  float gn = bih[2*H + li];
#pragma unroll
  for (int q = 0; q < E; q++){
    const float ev = e[q];
    gr = fmaf(Wih[(size_t)( li     )*H + q], ev, gr);
    gz = fmaf(Wih[(size_t)( H + li )*H + q], ev, gz);
    gn = fmaf(Wih[(size_t)(2*H + li)*H + q], ev, gn);
  }
  G[(size_t)(dir * N + idx) * H + li] =
      make_float4(-LOG2E * gr, -LOG2E * gz, 2.f * LOG2E * gn, 0.f);
}

__global__ __launch_bounds__(256) void pre_kernel(
    const float* __restrict__ emb_dp, const float* __restrict__ emb_cp,
    const float* __restrict__ Wih_dpf, const float* __restrict__ bih_dpf, const float* __restrict__ bhh_dpf,
    const float* __restrict__ Wih_dpb, const float* __restrict__ bih_dpb, const float* __restrict__ bhh_dpb,
    const float* __restrict__ Wih_cpf, const float* __restrict__ bih_cpf, const float* __restrict__ bhh_cpf,
    const float* __restrict__ Wih_cpb, const float* __restrict__ bih_cpb, const float* __restrict__ bhh_cpb,
    const float* __restrict__ stat, const float* __restrict__ fc_all_w, const float* __restrict__ fc_all_b,
    const float* __restrict__ fc_dp_b, const float* __restrict__ fc_cp_b,
    float4* __restrict__ Gdp, float4* __restrict__ Gcp, float* __restrict__ out)
{
  constexpr int NDP_E = 2 * 4096 * 9;    // 73728
  constexpr int NCP_E = 2 * 10000 * 11;  // 220000
  const int t = blockIdx.x * 256 + threadIdx.x;
  if (t < NDP_E){
    pre_entry<9>(t, emb_dp, Wih_dpf, bih_dpf, bhh_dpf, Wih_dpb, bih_dpb, bhh_dpb, Gdp, 4096);
  } else if (t < NDP_E + NCP_E){
    pre_entry<11>(t - NDP_E, emb_cp, Wih_cpf, bih_cpf, bhh_cpf, Wih_cpb, bih_cpb, bhh_cpb, Gcp, 10000);
  } else if (t < NDP_E + NCP_E + 4096){
    const int b = t - (NDP_E + NCP_E);
    float s = fc_all_b[0] + fc_all_w[20]*fc_dp_b[0] + fc_all_w[21]*fc_cp_b[0];
    const float* st = stat + (size_t)b * 20;
#pragma unroll
    for (int k = 0; k < 20; k++) s = fmaf(fc_all_w[k], st[k], s);
    out[b] = s;
  }
}

// ---------------------------------------------------------------------------
// Kernel 2: fused GRU — r6 skeleton, but h-broadcast via ds_bpermute_b32
// (register cross-lane pull). No LDS buffer, no barrier, no memory clobber:
// the wave executes one instruction at a time, so every lane's hmine register
// is current when the bpermutes issue.
// ---------------------------------------------------------------------------
template<int H, int GPW, int N>
DEVINL void gru_body(int blk,
    const int*   __restrict__ seq,  const float* __restrict__ tim,
    const float4* __restrict__ Gtab,
    const float* __restrict__ Wih_f, const float* __restrict__ Whh_f, const float* __restrict__ bhh_f,
    const float* __restrict__ Wih_b, const float* __restrict__ Whh_b, const float* __restrict__ bhh_b,
    const float* __restrict__ fc_w, const float* __restrict__ fc_all_w, int tail_idx,
    float* __restrict__ out)
{
  constexpr int S   = 512;
  constexpr int GPB = 4 * GPW;
  constexpr int NP  = (H + 1) / 2;

  const int tid  = threadIdx.x;
  const int wave = tid >> 6, lane = tid & 63;
  const int g_in_wave = lane / H;
  const int li = lane - g_in_wave * H;
  if (g_in_wave >= GPW) return;
  const int gid = blk * GPB + wave * GPW + g_in_wave;
  if (gid >= 8192) return;
  const int b   = gid & 4095;
  const int dir = gid >> 12;

  const float* Wih = dir ? Wih_b : Wih_f;
  const float* Whh = dir ? Whh_b : Whh_f;

  // bpermute byte-indices of this group's lanes (constant VGPRs)
  int bq[H];
#pragma unroll
  for (int q = 0; q < H; q++) bq[q] = (g_in_wave * H + q) * 4;

  // dt-column weights and recurrent rows, pre-scaled; packed as f32x2 pairs
  const float Wrd = -LOG2E      * Wih[( li      )*H + (H-1)];
  const float Wzd = -LOG2E      * Wih[( H + li  )*H + (H-1)];
  const float Wnd = 2.f * LOG2E * Wih[(2*H + li )*H + (H-1)];
  f32x2 Urp[NP], Uzp[NP], Unp[NP];
#pragma unroll
  for (int j = 0; j < NP; j++){
    const int q0 = 2*j, q1 = 2*j + 1;
    f32x2 v;
    v.x = -LOG2E * Whh[( li      )*H + q0];
    v.y = (q1 < H) ? -LOG2E * Whh[( li      )*H + q1] : 0.f;
    Urp[j] = v;
    v.x = -LOG2E * Whh[( H + li  )*H + q0];
    v.y = (q1 < H) ? -LOG2E * Whh[( H + li  )*H + q1] : 0.f;
    Uzp[j] = v;
    v.x = 2.f * LOG2E * Whh[(2*H + li )*H + q0];
    v.y = (q1 < H) ? 2.f * LOG2E * Whh[(2*H + li )*H + q1] : 0.f;
    Unp[j] = v;
  }
  const float bhn = 2.f * LOG2E * (dir ? bhh_b : bhh_f)[2*H + li];

  const int*    sp = seq + (size_t)b * S;
  const float*  tp = tim + (size_t)b * S;
  const float4* pG = Gtab + (size_t)(dir * N) * H + li;   // + idx*H per step

  f32x2 hp[NP];
#pragma unroll
  for (int j = 0; j < NP; j++){ f32x2 z0; z0.x = 0.f; z0.y = 0.f; hp[j] = z0; }
  float hmine = 0.f, prev = 0.f;

  int ic[4]; float tc[4];
  int icn[4] = {0,0,0,0}; float tcn[4] = {0,0,0,0};
  {
    const int p0 = dir ? (S - 4) : 0;
    int4   iv = *reinterpret_cast<const int4*  >(sp + p0);
    float4 tv = *reinterpret_cast<const float4*>(tp + p0);
    if (dir){ ic[0]=iv.w; ic[1]=iv.z; ic[2]=iv.y; ic[3]=iv.x;
              tc[0]=tv.w; tc[1]=tv.z; tc[2]=tv.y; tc[3]=tv.x; }
    else    { ic[0]=iv.x; ic[1]=iv.y; ic[2]=iv.z; ic[3]=iv.w;
              tc[0]=tv.x; tc[1]=tv.y; tc[2]=tv.z; tc[3]=tv.w; }
  }

  // depth-2 gather ring (r2-proven)
  float4 Gb[4];
  Gb[0] = pG[(size_t)ic[0] * H];
  Gb[1] = pG[(size_t)ic[1] * H];

#pragma unroll 1
  for (int c = 0; c < S/4; ++c){
    if (c < S/4 - 1){
      const int p0 = dir ? (S - 8 - 4*c) : (4*c + 4);
      int4   iv = *reinterpret_cast<const int4*  >(sp + p0);
      float4 tv = *reinterpret_cast<const float4*>(tp + p0);
      if (dir){ icn[0]=iv.w; icn[1]=iv.z; icn[2]=iv.y; icn[3]=iv.x;
                tcn[0]=tv.w; tcn[1]=tv.z; tcn[2]=tv.y; tcn[3]=tv.x; }
      else    { icn[0]=iv.x; icn[1]=iv.y; icn[2]=iv.z; icn[3]=iv.w;
                tcn[0]=tv.x; tcn[1]=tv.y; tcn[2]=tv.z; tcn[3]=tv.w; }
    }
#pragma unroll
    for (int k = 0; k < 4; k++){
      const float4 g4 = Gb[k];
      // prefetch step c*4+k+2 (stale icn on last chunk: valid in-range idx, unused)
      {
        const int pidx = (k==0) ? ic[2] : (k==1) ? ic[3] : (k==2) ? icn[0] : icn[1];
        Gb[(k+2)&3] = pG[(size_t)pidx * H];
      }

      const float tcur = tc[k];
      const float dtv = fmaxf(tcur - prev, 0.f); prev = tcur;

      f32x2 aR, aZ, aN;
      aR.x = fmaf(Wrd, dtv, g4.x); aR.y = 0.f;
      aZ.x = fmaf(Wzd, dtv, g4.y); aZ.y = 0.f;
      aN.x = bhn;                  aN.y = 0.f;
#pragma unroll
      for (int j = 0; j < NP; j++){
        aR = __builtin_elementwise_fma(Urp[j], hp[j], aR);
        aZ = __builtin_elementwise_fma(Uzp[j], hp[j], aZ);
        aN = __builtin_elementwise_fma(Unp[j], hp[j], aN);
      }
      const float ar = aR.x + aR.y;        // already -log2e * (pre-activation)
      const float az = aZ.x + aZ.y;
      const float hn = aN.x + aN.y;        // already 2*log2e * (Un·h + bhn)
      const float an = fmaf(Wnd, dtv, g4.z);

      const float ea = fexp2(ar), eb = fexp2(az);
      const float pa = 1.f + ea,  pb = 1.f + eb;
      const float inv = frcp(pa * pb);     // shared rcp: r = 1/pa, z = 1/pb
      const float r = pb * inv;
      const float z = pa * inv;
      const float ec = fexp2(fmaf(r, hn, an));
      const float n  = fmaf(-2.f, frcp(1.f + ec), 1.f);
      hmine = fmaf(z, hmine - n, n);       // (1-z)*n + z*h

      // h broadcast: register cross-lane pull, no LDS / barrier / clobber
      const int hm_i = __float_as_int(hmine);
#pragma unroll
      for (int j = 0; j < NP; j++){
        hp[j].x = __int_as_float(__builtin_amdgcn_ds_bpermute(bq[2*j], hm_i));
        if (2*j + 1 < H)
          hp[j].y = __int_as_float(__builtin_amdgcn_ds_bpermute(bq[2*j+1], hm_i));
        else
          hp[j].y = 0.f;                   // pad element (weight 0)
      }
    }
#pragma unroll
    for (int k2 = 0; k2 < 4; k2++){ ic[k2] = icn[k2]; tc[k2] = tcn[k2]; }
  }

  // one atomic per sequence (lane 0 holds full h in hp pairs)
  if (li == 0){
    float dot = 0.f;
#pragma unroll
    for (int j = 0; j < NP; j++){
      dot = fmaf(fc_w[dir*H + 2*j], hp[j].x, dot);
      if (2*j + 1 < H) dot = fmaf(fc_w[dir*H + 2*j + 1], hp[j].y, dot);
    }
    atomicAdd(out + b, fc_all_w[tail_idx] * dot);
  }
}

__global__ __launch_bounds__(256) void gru_fused(
    const int* __restrict__ dp,  const float* __restrict__ dp_t,
    const int* __restrict__ cp,  const float* __restrict__ cp_t,
    const float4* __restrict__ Gdp, const float4* __restrict__ Gcp,
    const float* __restrict__ Wih_dpf, const float* __restrict__ Whh_dpf, const float* __restrict__ bhh_dpf,
    const float* __restrict__ Wih_dpb, const float* __restrict__ Whh_dpb, const float* __restrict__ bhh_dpb,
    const float* __restrict__ Wih_cpf, const float* __restrict__ Whh_cpf, const float* __restrict__ bhh_cpf,
    const float* __restrict__ Wih_cpb, const float* __restrict__ Whh_cpb, const float* __restrict__ bhh_cpb,
    const float* __restrict__ fc_dp_w, const float* __restrict__ fc_cp_w, const float* __restrict__ fc_all_w,
    float* __restrict__ out, int DP_BLOCKS)
{
  if ((int)blockIdx.x < DP_BLOCKS){
    gru_body<9, 7, 4096>(blockIdx.x, dp, dp_t, Gdp,
        Wih_dpf, Whh_dpf, bhh_dpf, Wih_dpb, Whh_dpb, bhh_dpb,
        fc_dp_w, fc_all_w, 20, out);
  } else {
    gru_body<11, 5, 10000>(blockIdx.x - DP_BLOCKS, cp, cp_t, Gcp,
        Wih_cpf, Whh_cpf, bhh_cpf, Wih_cpb, Whh_cpb, bhh_cpb,
        fc_cp_w, fc_all_w, 21, out);
  }
}

extern "C" void kernel_launch(void* const* d_in, const int* in_sizes, int n_in,
                              void* d_out, int out_size, void* d_ws, size_t ws_size,
                              hipStream_t stream)
{
  const float* stat   = (const float*)d_in[0];
  const int*   dp     = (const int*)  d_in[1];
  const int*   cp     = (const int*)  d_in[2];
  const float* dp_t   = (const float*)d_in[3];
  const float* cp_t   = (const float*)d_in[4];
  const float* emb_dp = (const float*)d_in[5];
  const float* emb_cp = (const float*)d_in[6];

  const float* Wih_dpf = (const float*)d_in[7];
  const float* Whh_dpf = (const float*)d_in[8];
  const float* bih_dpf = (const float*)d_in[9];
  const float* bhh_dpf = (const float*)d_in[10];
  const float* Wih_dpb = (const float*)d_in[11];
  const float* Whh_dpb = (const float*)d_in[12];
  const float* bih_dpb = (const float*)d_in[13];
  const float* bhh_dpb = (const float*)d_in[14];
  const float* Wih_cpf = (const float*)d_in[15];
  const float* Whh_cpf = (const float*)d_in[16];
  const float* bih_cpf = (const float*)d_in[17];
  const float* bhh_cpf = (const float*)d_in[18];
  const float* Wih_cpb = (const float*)d_in[19];
  const float* Whh_cpb = (const float*)d_in[20];
  const float* bih_cpb = (const float*)d_in[21];
  const float* bhh_cpb = (const float*)d_in[22];

  const float* fc_dp_w  = (const float*)d_in[23];
  const float* fc_dp_b  = (const float*)d_in[24];
  const float* fc_cp_w  = (const float*)d_in[25];
  const float* fc_cp_b  = (const float*)d_in[26];
  const float* fc_all_w = (const float*)d_in[27];
  const float* fc_all_b = (const float*)d_in[28];

  float* out = (float*)d_out;

  // workspace: dp table (2*4096*9 float4 = 1.18 MB), cp table (2*10000*11 float4 = 3.52 MB)
  float4* Gdp = (float4*)d_ws;
  float4* Gcp = (float4*)((char*)d_ws + (size_t)(2*4096*9) * sizeof(float4));

  {
    const int total = 2*4096*9 + 2*10000*11 + 4096;
    const int blocks = (total + 255) / 256;
    pre_kernel<<<blocks, 256, 0, stream>>>(
        emb_dp, emb_cp,
        Wih_dpf, bih_dpf, bhh_dpf, Wih_dpb, bih_dpb, bhh_dpb,
        Wih_cpf, bih_cpf, bhh_cpf, Wih_cpb, bih_cpb, bhh_cpb,
        stat, fc_all_w, fc_all_b, fc_dp_b, fc_cp_b,
        Gdp, Gcp, out);
  }

  {
    const int DP_BLOCKS = (8192 + 27) / 28;   // H=9,  7 groups/wave
    const int CP_BLOCKS = (8192 + 19) / 20;   // H=11, 5 groups/wave
    gru_fused<<<DP_BLOCKS + CP_BLOCKS, 256, 0, stream>>>(
        dp, dp_t, cp, cp_t, Gdp, Gcp,
        Wih_dpf, Whh_dpf, bhh_dpf, Wih_dpb, Whh_dpb, bhh_dpb,
        Wih_cpf, Whh_cpf, bhh_cpf, Wih_cpb, Whh_cpb, bhh_cpb,
        fc_dp_w, fc_cp_w, fc_all_w, out, DP_BLOCKS);
  }
}

// Round 8
// 189.130 us; speedup vs baseline: 1.1366x; 1.1366x over previous
//
#include <hip/hip_runtime.h>

#define DEVINL __device__ __forceinline__

typedef float    f32x2 __attribute__((ext_vector_type(2)));
typedef _Float16 h4v   __attribute__((ext_vector_type(4)));

DEVINL float fexp2(float x){ return __builtin_amdgcn_exp2f(x); }
DEVINL float frcp (float x){ return __builtin_amdgcn_rcpf(x); }

#define LOG2E 1.4426950408889634f

// quad-broadcast: value of quad-lane QS replicated to all 4 lanes of the quad.
// Full-rate VALU DPP — no DS pipe, no barrier.
DEVINL float qbc(float v, int qs){
  const int s = __float_as_int(v);
  int r;
  switch (qs & 3){
#if __has_builtin(__builtin_amdgcn_mov_dpp)
    case 0:  r = __builtin_amdgcn_mov_dpp(s, 0x00, 0xF, 0xF, true); break;
    case 1:  r = __builtin_amdgcn_mov_dpp(s, 0x55, 0xF, 0xF, true); break;
    case 2:  r = __builtin_amdgcn_mov_dpp(s, 0xAA, 0xF, 0xF, true); break;
    default: r = __builtin_amdgcn_mov_dpp(s, 0xFF, 0xF, 0xF, true); break;
#else
    case 0:  r = __builtin_amdgcn_update_dpp(0, s, 0x00, 0xF, 0xF, true); break;
    case 1:  r = __builtin_amdgcn_update_dpp(0, s, 0x55, 0xF, 0xF, true); break;
    case 2:  r = __builtin_amdgcn_update_dpp(0, s, 0xAA, 0xF, 0xF, true); break;
    default: r = __builtin_amdgcn_update_dpp(0, s, 0xFF, 0xF, 0xF, true); break;
#endif
  }
  return __int_as_float(r);
}

// ---------------------------------------------------------------------------
// Kernel 1: precompute per-(dir, idx, lane) input-gate table, f16, PRE-SCALED:
//   G = { -l2e*(Wr_e·e + br), -l2e*(Wz_e·e + bz), 2*l2e*(Wn_e·e + bn_ih), 0 }
// dp 0.59 MB + cp 1.76 MB -> L2-resident. Plus static part of out[b].
// ---------------------------------------------------------------------------
template<int H>
DEVINL void pre_entry(int t, const float* __restrict__ emb,
                      const float* __restrict__ Wih_f, const float* __restrict__ bih_f, const float* __restrict__ bhh_f,
                      const float* __restrict__ Wih_b, const float* __restrict__ bih_b, const float* __restrict__ bhh_b,
                      h4v* __restrict__ G, int N)
{
  constexpr int E = H - 1;
  const int dir = t / (N * H);
  const int r   = t - dir * (N * H);
  const int idx = r / H;
  const int li  = r - idx * H;
  const float* Wih = dir ? Wih_b : Wih_f;
  const float* bih = dir ? bih_b : bih_f;
  const float* bhh = dir ? bhh_b : bhh_f;
  const float* e = emb + (size_t)idx * E;
  float gr = bih[li]       + bhh[li];
  float gz = bih[H + li]   + bhh[H + li];
  float gn = bih[2*H + li];
#pragma unroll
  for (int q = 0; q < E; q++){
    const float ev = e[q];
    gr = fmaf(Wih[(size_t)( li     )*H + q], ev, gr);
    gz = fmaf(Wih[(size_t)( H + li )*H + q], ev, gz);
    gn = fmaf(Wih[(size_t)(2*H + li)*H + q], ev, gn);
  }
  h4v g;
  g.x = (_Float16)(-LOG2E * gr);
  g.y = (_Float16)(-LOG2E * gz);
  g.z = (_Float16)(2.f * LOG2E * gn);
  g.w = (_Float16)0.f;
  G[(size_t)(dir * N + idx) * H + li] = g;
}

__global__ __launch_bounds__(256) void pre_kernel(
    const float* __restrict__ emb_dp, const float* __restrict__ emb_cp,
    const float* __restrict__ Wih_dpf, const float* __restrict__ bih_dpf, const float* __restrict__ bhh_dpf,
    const float* __restrict__ Wih_dpb, const float* __restrict__ bih_dpb, const float* __restrict__ bhh_dpb,
    const float* __restrict__ Wih_cpf, const float* __restrict__ bih_cpf, const float* __restrict__ bhh_cpf,
    const float* __restrict__ Wih_cpb, const float* __restrict__ bih_cpb, const float* __restrict__ bhh_cpb,
    const float* __restrict__ stat, const float* __restrict__ fc_all_w, const float* __restrict__ fc_all_b,
    const float* __restrict__ fc_dp_b, const float* __restrict__ fc_cp_b,
    h4v* __restrict__ Gdp, h4v* __restrict__ Gcp, float* __restrict__ out)
{
  constexpr int NDP_E = 2 * 4096 * 9;    // 73728
  constexpr int NCP_E = 2 * 10000 * 11;  // 220000
  const int t = blockIdx.x * 256 + threadIdx.x;
  if (t < NDP_E){
    pre_entry<9>(t, emb_dp, Wih_dpf, bih_dpf, bhh_dpf, Wih_dpb, bih_dpb, bhh_dpb, Gdp, 4096);
  } else if (t < NDP_E + NCP_E){
    pre_entry<11>(t - NDP_E, emb_cp, Wih_cpf, bih_cpf, bhh_cpf, Wih_cpb, bih_cpb, bhh_cpb, Gcp, 10000);
  } else if (t < NDP_E + NCP_E + 4096){
    const int b = t - (NDP_E + NCP_E);
    float s = fc_all_b[0] + fc_all_w[20]*fc_dp_b[0] + fc_all_w[21]*fc_cp_b[0];
    const float* st = stat + (size_t)b * 20;
#pragma unroll
    for (int k = 0; k < 20; k++) s = fmaf(fc_all_w[k], st[k], s);
    out[b] = s;
  }
}

// ---------------------------------------------------------------------------
// Kernel 2: fused GRU — 4 lanes per sequence, 16 sequences per wave.
// Quad-lane q owns hidden elements {q, q+4, q+8} (clamped pads; pad weights 0).
// Cross-lane h share via DPP quad_perm (VALU) — ZERO LDS/DS ops.
// 1024 one-wave blocks = 1 wave/SIMD; __launch_bounds__(64,1) -> full VGPR file.
// ---------------------------------------------------------------------------
template<int H, int N>
DEVINL void gru16(int wid,
    const int* __restrict__ seq, const float* __restrict__ tim,
    const h4v* __restrict__ Gtab,
    const float* __restrict__ Wih_f, const float* __restrict__ Whh_f, const float* __restrict__ bhh_f,
    const float* __restrict__ Wih_b, const float* __restrict__ Whh_b, const float* __restrict__ bhh_b,
    const float* __restrict__ fc_w, const float* __restrict__ fc_all_w, int tail_idx,
    float* __restrict__ out)
{
  constexpr int S  = 512;
  constexpr int NP = (H + 1) / 2;        // f32x2 pairs (2*NP >= H, pad weight 0)
  const int lane = threadIdx.x & 63;
  const int qsel = lane & 3;
  const int gid  = wid * 16 + (lane >> 2);
  const int b    = gid & 4095;
  const int dir  = gid >> 12;

  const float* Wih = dir ? Wih_b : Wih_f;
  const float* Whh = dir ? Whh_b : Whh_f;
  const float* bhh = dir ? bhh_b : bhh_f;

  // owned elements (clamped: pad elements duplicate row H-1; their outputs are dead)
  int el[3];
#pragma unroll
  for (int j = 0; j < 3; j++){ const int e = qsel + 4*j; el[j] = (e < H) ? e : (H-1); }

  // register-resident weights, pre-scaled
  float Wrd[3], Wzd[3], Wnd[3], bhn3[3];
  f32x2 Ur[3][NP], Uz[3][NP], Un[3][NP];
#pragma unroll
  for (int j = 0; j < 3; j++){
    const int e = el[j];
    Wrd[j]  = -LOG2E    * Wih[( e      )*H + (H-1)];
    Wzd[j]  = -LOG2E    * Wih[( H + e  )*H + (H-1)];
    Wnd[j]  = 2.f*LOG2E * Wih[(2*H + e )*H + (H-1)];
    bhn3[j] = 2.f*LOG2E * bhh[2*H + e];
#pragma unroll
    for (int p = 0; p < NP; p++){
      const int q0 = 2*p, q1 = 2*p + 1;
      f32x2 v;
      v.x = -LOG2E * Whh[( e )*H + q0];
      v.y = (q1 < H) ? -LOG2E * Whh[( e )*H + q1] : 0.f;
      Ur[j][p] = v;
      v.x = -LOG2E * Whh[( H + e )*H + q0];
      v.y = (q1 < H) ? -LOG2E * Whh[( H + e )*H + q1] : 0.f;
      Uz[j][p] = v;
      v.x = 2.f*LOG2E * Whh[(2*H + e )*H + q0];
      v.y = (q1 < H) ? 2.f*LOG2E * Whh[(2*H + e )*H + q1] : 0.f;
      Un[j][p] = v;
    }
  }

  const int*   sp = seq + (size_t)b * S;
  const float* tp = tim + (size_t)b * S;
  const h4v*   pG = Gtab + (size_t)dir * N * H;

  f32x2 hp[NP];
#pragma unroll
  for (int p = 0; p < NP; p++){ hp[p].x = 0.f; hp[p].y = 0.f; }
  float hm[3] = {0.f, 0.f, 0.f};
  float prev = 0.f;

  int ic[4]; float tc[4];
  int icn[4] = {0,0,0,0}; float tcn[4] = {0,0,0,0};
  {
    const int p0 = dir ? (S - 4) : 0;
    int4   iv = *reinterpret_cast<const int4*  >(sp + p0);
    float4 tv = *reinterpret_cast<const float4*>(tp + p0);
    if (dir){ ic[0]=iv.w; ic[1]=iv.z; ic[2]=iv.y; ic[3]=iv.x;
              tc[0]=tv.w; tc[1]=tv.z; tc[2]=tv.y; tc[3]=tv.x; }
    else    { ic[0]=iv.x; ic[1]=iv.y; ic[2]=iv.z; ic[3]=iv.w;
              tc[0]=tv.x; tc[1]=tv.y; tc[2]=tv.z; tc[3]=tv.w; }
  }

  // depth-2 gather ring, one slot set per owned element (all indices static)
  h4v Gb[3][4];
#pragma unroll
  for (int j = 0; j < 3; j++){
    Gb[j][0] = pG[(size_t)ic[0] * H + el[j]];
    Gb[j][1] = pG[(size_t)ic[1] * H + el[j]];
  }

#pragma unroll 1
  for (int c = 0; c < S/4; ++c){
    if (c < S/4 - 1){
      const int p0 = dir ? (S - 8 - 4*c) : (4*c + 4);
      int4   iv = *reinterpret_cast<const int4*  >(sp + p0);
      float4 tv = *reinterpret_cast<const float4*>(tp + p0);
      if (dir){ icn[0]=iv.w; icn[1]=iv.z; icn[2]=iv.y; icn[3]=iv.x;
                tcn[0]=tv.w; tcn[1]=tv.z; tcn[2]=tv.y; tcn[3]=tv.x; }
      else    { icn[0]=iv.x; icn[1]=iv.y; icn[2]=iv.z; icn[3]=iv.w;
                tcn[0]=tv.x; tcn[1]=tv.y; tcn[2]=tv.z; tcn[3]=tv.w; }
    }
#pragma unroll
    for (int k = 0; k < 4; k++){
      // prefetch step c*4+k+2 (stale icn on last chunk: valid in-range idx, unused)
      {
        const int pidx = (k==0) ? ic[2] : (k==1) ? ic[3] : (k==2) ? icn[0] : icn[1];
#pragma unroll
        for (int j = 0; j < 3; j++)
          Gb[j][(k+2)&3] = pG[(size_t)pidx * H + el[j]];
      }

      const float tcur = tc[k];
      const float dtv = fmaxf(tcur - prev, 0.f); prev = tcur;

#pragma unroll
      for (int j = 0; j < 3; j++){
        const h4v g4 = Gb[j][k];
        f32x2 aR, aZ, aN;
        aR.x = fmaf(Wrd[j], dtv, (float)g4.x); aR.y = 0.f;
        aZ.x = fmaf(Wzd[j], dtv, (float)g4.y); aZ.y = 0.f;
        aN.x = bhn3[j];                        aN.y = 0.f;
#pragma unroll
        for (int p = 0; p < NP; p++){
          aR = __builtin_elementwise_fma(Ur[j][p], hp[p], aR);
          aZ = __builtin_elementwise_fma(Uz[j][p], hp[p], aZ);
          aN = __builtin_elementwise_fma(Un[j][p], hp[p], aN);
        }
        const float ar = aR.x + aR.y;          // -l2e * pre_r
        const float az = aZ.x + aZ.y;          // -l2e * pre_z
        const float hn = aN.x + aN.y;          // 2*l2e * (Un·h + bhn)
        const float an = fmaf(Wnd[j], dtv, (float)g4.z);

        const float ea = fexp2(ar), eb = fexp2(az);
        const float pa = 1.f + ea,  pb = 1.f + eb;
        const float inv = frcp(pa * pb);       // r = 1/pa, z = 1/pb
        const float r = pb * inv;
        const float z = pa * inv;
        const float ec = fexp2(fmaf(r, hn, an));
        const float n  = fmaf(-2.f, frcp(1.f + ec), 1.f);
        hm[j] = fmaf(z, hm[j] - n, n);         // (1-z)*n + z*h
      }

      // h broadcast: DPP quad_perm (VALU), pads zeroed (keeps 0-weight dots NaN-free)
      float hv[2*NP];
#pragma unroll
      for (int e = 0; e < H; e++) hv[e] = qbc(hm[e >> 2], e & 3);
#pragma unroll
      for (int e = H; e < 2*NP; e++) hv[e] = 0.f;
#pragma unroll
      for (int p = 0; p < NP; p++){ hp[p].x = hv[2*p]; hp[p].y = hv[2*p+1]; }
    }
#pragma unroll
    for (int k2 = 0; k2 < 4; k2++){ ic[k2] = icn[k2]; tc[k2] = tcn[k2]; }
  }

  // one atomic per sequence (quad-lane 0; h fully replicated in hp)
  if (qsel == 0){
    float dot = 0.f;
#pragma unroll
    for (int p = 0; p < NP; p++){
      dot = fmaf(fc_w[dir*H + 2*p], hp[p].x, dot);
      if (2*p + 1 < H) dot = fmaf(fc_w[dir*H + 2*p + 1], hp[p].y, dot);
    }
    atomicAdd(out + b, fc_all_w[tail_idx] * dot);
  }
}

__global__ __launch_bounds__(64, 1) void gru_fused(
    const int* __restrict__ dp,  const float* __restrict__ dp_t,
    const int* __restrict__ cp,  const float* __restrict__ cp_t,
    const h4v* __restrict__ Gdp, const h4v* __restrict__ Gcp,
    const float* __restrict__ Wih_dpf, const float* __restrict__ Whh_dpf, const float* __restrict__ bhh_dpf,
    const float* __restrict__ Wih_dpb, const float* __restrict__ Whh_dpb, const float* __restrict__ bhh_dpb,
    const float* __restrict__ Wih_cpf, const float* __restrict__ Whh_cpf, const float* __restrict__ bhh_cpf,
    const float* __restrict__ Wih_cpb, const float* __restrict__ Whh_cpb, const float* __restrict__ bhh_cpb,
    const float* __restrict__ fc_dp_w, const float* __restrict__ fc_cp_w, const float* __restrict__ fc_all_w,
    float* __restrict__ out, int DP_BLOCKS)
{
  if ((int)blockIdx.x < DP_BLOCKS){
    gru16<9, 4096>(blockIdx.x, dp, dp_t, Gdp,
        Wih_dpf, Whh_dpf, bhh_dpf, Wih_dpb, Whh_dpb, bhh_dpb,
        fc_dp_w, fc_all_w, 20, out);
  } else {
    gru16<11, 10000>(blockIdx.x - DP_BLOCKS, cp, cp_t, Gcp,
        Wih_cpf, Whh_cpf, bhh_cpf, Wih_cpb, Whh_cpb, bhh_cpb,
        fc_cp_w, fc_all_w, 21, out);
  }
}

extern "C" void kernel_launch(void* const* d_in, const int* in_sizes, int n_in,
                              void* d_out, int out_size, void* d_ws, size_t ws_size,
                              hipStream_t stream)
{
  const float* stat   = (const float*)d_in[0];
  const int*   dp     = (const int*)  d_in[1];
  const int*   cp     = (const int*)  d_in[2];
  const float* dp_t   = (const float*)d_in[3];
  const float* cp_t   = (const float*)d_in[4];
  const float* emb_dp = (const float*)d_in[5];
  const float* emb_cp = (const float*)d_in[6];

  const float* Wih_dpf = (const float*)d_in[7];
  const float* Whh_dpf = (const float*)d_in[8];
  const float* bih_dpf = (const float*)d_in[9];
  const float* bhh_dpf = (const float*)d_in[10];
  const float* Wih_dpb = (const float*)d_in[11];
  const float* Whh_dpb = (const float*)d_in[12];
  const float* bih_dpb = (const float*)d_in[13];
  const float* bhh_dpb = (const float*)d_in[14];
  const float* Wih_cpf = (const float*)d_in[15];
  const float* Whh_cpf = (const float*)d_in[16];
  const float* bih_cpf = (const float*)d_in[17];
  const float* bhh_cpf = (const float*)d_in[18];
  const float* Wih_cpb = (const float*)d_in[19];
  const float* Whh_cpb = (const float*)d_in[20];
  const float* bih_cpb = (const float*)d_in[21];
  const float* bhh_cpb = (const float*)d_in[22];

  const float* fc_dp_w  = (const float*)d_in[23];
  const float* fc_dp_b  = (const float*)d_in[24];
  const float* fc_cp_w  = (const float*)d_in[25];
  const float* fc_cp_b  = (const float*)d_in[26];
  const float* fc_all_w = (const float*)d_in[27];
  const float* fc_all_b = (const float*)d_in[28];

  float* out = (float*)d_out;

  // workspace: dp table (2*4096*9 * 8B = 0.59 MB), cp table (2*10000*11 * 8B = 1.76 MB)
  h4v* Gdp = (h4v*)d_ws;
  h4v* Gcp = (h4v*)((char*)d_ws + (size_t)(2*4096*9) * sizeof(h4v));

  {
    const int total = 2*4096*9 + 2*10000*11 + 4096;
    const int blocks = (total + 255) / 256;
    pre_kernel<<<blocks, 256, 0, stream>>>(
        emb_dp, emb_cp,
        Wih_dpf, bih_dpf, bhh_dpf, Wih_dpb, bih_dpb, bhh_dpb,
        Wih_cpf, bih_cpf, bhh_cpf, Wih_cpb, bih_cpb, bhh_cpb,
        stat, fc_all_w, fc_all_b, fc_dp_b, fc_cp_b,
        Gdp, Gcp, out);
  }

  {
    const int DP_BLOCKS = 8192 / 16;   // 512 one-wave blocks (16 seqs each)
    const int CP_BLOCKS = 8192 / 16;   // 512
    gru_fused<<<DP_BLOCKS + CP_BLOCKS, 64, 0, stream>>>(
        dp, dp_t, cp, cp_t, Gdp, Gcp,
        Wih_dpf, Whh_dpf, bhh_dpf, Wih_dpb, Whh_dpb, bhh_dpb,
        Wih_cpf, Whh_cpf, bhh_cpf, Wih_cpb, Whh_cpb, bhh_cpb,
        fc_dp_w, fc_cp_w, fc_all_w, out, DP_BLOCKS);
  }
}

// Round 9
// 182.452 us; speedup vs baseline: 1.1782x; 1.0366x over previous
//
#include <hip/hip_runtime.h>

#define DEVINL __device__ __forceinline__

typedef float f32x2 __attribute__((ext_vector_type(2)));

DEVINL float fexp2(float x){ return __builtin_amdgcn_exp2f(x); }
DEVINL float frcp (float x){ return __builtin_amdgcn_rcpf(x); }

#define LOG2E 1.4426950408889634f

// ---------------------------------------------------------------------------
// Kernel 1: precompute per-(dir, idx, lane) input-gate table, PRE-SCALED:
//   G = { -log2e * (Wr_e·e + bih_r + bhh_r),
//         -log2e * (Wz_e·e + bih_z + bhh_z),
//         2*log2e * (Wn_e·e + bih_n), 0 }
// Plus the static part of out[b].
// ---------------------------------------------------------------------------
template<int H>
DEVINL void pre_entry(int t, const float* __restrict__ emb,
                      const float* __restrict__ Wih_f, const float* __restrict__ bih_f, const float* __restrict__ bhh_f,
                      const float* __restrict__ Wih_b, const float* __restrict__ bih_b, const float* __restrict__ bhh_b,
                      float4* __restrict__ G, int N)
{
  constexpr int E = H - 1;
  const int dir = t / (N * H);
  const int r   = t - dir * (N * H);
  const int idx = r / H;
  const int li  = r - idx * H;
  const float* Wih = dir ? Wih_b : Wih_f;
  const float* bih = dir ? bih_b : bih_f;
  const float* bhh = dir ? bhh_b : bhh_f;
  const float* e = emb + (size_t)idx * E;
  float gr = bih[li]       + bhh[li];
  float gz = bih[H + li]   + bhh[H + li];
  float gn = bih[2*H + li];
#pragma unroll
  for (int q = 0; q < E; q++){
    const float ev = e[q];
    gr = fmaf(Wih[(size_t)( li     )*H + q], ev, gr);
    gz = fmaf(Wih[(size_t)( H + li )*H + q], ev, gz);
    gn = fmaf(Wih[(size_t)(2*H + li)*H + q], ev, gn);
  }
  G[(size_t)(dir * N + idx) * H + li] =
      make_float4(-LOG2E * gr, -LOG2E * gz, 2.f * LOG2E * gn, 0.f);
}

__global__ __launch_bounds__(256) void pre_kernel(
    const float* __restrict__ emb_dp, const float* __restrict__ emb_cp,
    const float* __restrict__ Wih_dpf, const float* __restrict__ bih_dpf, const float* __restrict__ bhh_dpf,
    const float* __restrict__ Wih_dpb, const float* __restrict__ bih_dpb, const float* __restrict__ bhh_dpb,
    const float* __restrict__ Wih_cpf, const float* __restrict__ bih_cpf, const float* __restrict__ bhh_cpf,
    const float* __restrict__ Wih_cpb, const float* __restrict__ bih_cpb, const float* __restrict__ bhh_cpb,
    const float* __restrict__ stat, const float* __restrict__ fc_all_w, const float* __restrict__ fc_all_b,
    const float* __restrict__ fc_dp_b, const float* __restrict__ fc_cp_b,
    float4* __restrict__ Gdp, float4* __restrict__ Gcp, float* __restrict__ out)
{
  constexpr int NDP_E = 2 * 4096 * 9;    // 73728
  constexpr int NCP_E = 2 * 10000 * 11;  // 220000
  const int t = blockIdx.x * 256 + threadIdx.x;
  if (t < NDP_E){
    pre_entry<9>(t, emb_dp, Wih_dpf, bih_dpf, bhh_dpf, Wih_dpb, bih_dpb, bhh_dpb, Gdp, 4096);
  } else if (t < NDP_E + NCP_E){
    pre_entry<11>(t - NDP_E, emb_cp, Wih_cpf, bih_cpf, bhh_cpf, Wih_cpb, bih_cpb, bhh_cpb, Gcp, 10000);
  } else if (t < NDP_E + NCP_E + 4096){
    const int b = t - (NDP_E + NCP_E);
    float s = fc_all_b[0] + fc_all_w[20]*fc_dp_b[0] + fc_all_w[21]*fc_cp_b[0];
    const float* st = stat + (size_t)b * 20;
#pragma unroll
    for (int k = 0; k < 20; k++) s = fmaf(fc_all_w[k], st[k], s);
    out[b] = s;
  }
}

// ---------------------------------------------------------------------------
// Kernel 2: fused GRU — r6 skeleton with CHAIN surgery:
//  (1) independent rcps for r and z (no shared-rcp cross-coupling),
//  (2) LDS broadcast software-pipelined: reads ISSUED right after the write
//      (step bottom), but CONSUMED at the next step's top — the lgkmcnt wait
//      lands at the use point, overlapping the DS round trip with the
//      backedge + prefetch + dt work.
// ---------------------------------------------------------------------------
template<int H, int GPW, int N>
DEVINL void gru_body(int blk,
    const int*   __restrict__ seq,  const float* __restrict__ tim,
    const float4* __restrict__ Gtab,
    const float* __restrict__ Wih_f, const float* __restrict__ Whh_f, const float* __restrict__ bhh_f,
    const float* __restrict__ Wih_b, const float* __restrict__ Whh_b, const float* __restrict__ bhh_b,
    const float* __restrict__ fc_w, const float* __restrict__ fc_all_w, int tail_idx,
    float* __restrict__ out, float* hbuf)
{
  constexpr int S   = 512;
  constexpr int GPB = 4 * GPW;
  constexpr int NP  = (H + 1) / 2;

  const int tid  = threadIdx.x;
  const int wave = tid >> 6, lane = tid & 63;
  const int g_in_wave = lane / H;
  const int li = lane - g_in_wave * H;
  if (g_in_wave >= GPW) return;
  const int gid = blk * GPB + wave * GPW + g_in_wave;
  if (gid >= 8192) return;
  const int b   = gid & 4095;
  const int dir = gid >> 12;

  const float* Wih = dir ? Wih_b : Wih_f;
  const float* Whh = dir ? Whh_b : Whh_f;

  // dt-column weights and recurrent rows, pre-scaled; packed as f32x2 pairs
  const float Wrd = -LOG2E      * Wih[( li      )*H + (H-1)];
  const float Wzd = -LOG2E      * Wih[( H + li  )*H + (H-1)];
  const float Wnd = 2.f * LOG2E * Wih[(2*H + li )*H + (H-1)];
  f32x2 Urp[NP], Uzp[NP], Unp[NP];
#pragma unroll
  for (int j = 0; j < NP; j++){
    const int q0 = 2*j, q1 = 2*j + 1;
    f32x2 v;
    v.x = -LOG2E * Whh[( li      )*H + q0];
    v.y = (q1 < H) ? -LOG2E * Whh[( li      )*H + q1] : 0.f;
    Urp[j] = v;
    v.x = -LOG2E * Whh[( H + li  )*H + q0];
    v.y = (q1 < H) ? -LOG2E * Whh[( H + li  )*H + q1] : 0.f;
    Uzp[j] = v;
    v.x = 2.f * LOG2E * Whh[(2*H + li )*H + q0];
    v.y = (q1 < H) ? 2.f * LOG2E * Whh[(2*H + li )*H + q1] : 0.f;
    Unp[j] = v;
  }
  const float bhn = 2.f * LOG2E * (dir ? bhh_b : bhh_f)[2*H + li];

  const int*    sp = seq + (size_t)b * S;
  const float*  tp = tim + (size_t)b * S;
  const float4* pG = Gtab + (size_t)(dir * N) * H + li;   // + idx*H per step

  const int gb = (wave * GPW + g_in_wave) * 20;   // 80B slot stride
  if (li == 0) hbuf[gb + H] = 0.f;                // zero the pad element

  // loop-carried broadcast temps (h at step t-1); consumed at step top
  float4 h03 = make_float4(0.f,0.f,0.f,0.f);
  float4 h47 = make_float4(0.f,0.f,0.f,0.f);
  float4 h8b = make_float4(0.f,0.f,0.f,0.f);
  float2 h8p = make_float2(0.f,0.f);

  float hmine = 0.f, prev = 0.f;

  int ic[4]; float tc[4];
  int icn[4] = {0,0,0,0}; float tcn[4] = {0,0,0,0};
  {
    const int p0 = dir ? (S - 4) : 0;
    int4   iv = *reinterpret_cast<const int4*  >(sp + p0);
    float4 tv = *reinterpret_cast<const float4*>(tp + p0);
    if (dir){ ic[0]=iv.w; ic[1]=iv.z; ic[2]=iv.y; ic[3]=iv.x;
              tc[0]=tv.w; tc[1]=tv.z; tc[2]=tv.y; tc[3]=tv.x; }
    else    { ic[0]=iv.x; ic[1]=iv.y; ic[2]=iv.z; ic[3]=iv.w;
              tc[0]=tv.x; tc[1]=tv.y; tc[2]=tv.z; tc[3]=tv.w; }
  }

  // depth-2 gather ring (r2-proven)
  float4 Gb[4];
  Gb[0] = pG[(size_t)ic[0] * H];
  Gb[1] = pG[(size_t)ic[1] * H];

#pragma unroll 1
  for (int c = 0; c < S/4; ++c){
    if (c < S/4 - 1){
      const int p0 = dir ? (S - 8 - 4*c) : (4*c + 4);
      int4   iv = *reinterpret_cast<const int4*  >(sp + p0);
      float4 tv = *reinterpret_cast<const float4*>(tp + p0);
      if (dir){ icn[0]=iv.w; icn[1]=iv.z; icn[2]=iv.y; icn[3]=iv.x;
                tcn[0]=tv.w; tcn[1]=tv.z; tcn[2]=tv.y; tcn[3]=tv.x; }
      else    { icn[0]=iv.x; icn[1]=iv.y; icn[2]=iv.z; icn[3]=iv.w;
                tcn[0]=tv.x; tcn[1]=tv.y; tcn[2]=tv.z; tcn[3]=tv.w; }
    }
#pragma unroll
    for (int k = 0; k < 4; k++){
      const float4 g4 = Gb[k];
      // prefetch step c*4+k+2 (stale icn on last chunk: valid in-range idx, unused)
      {
        const int pidx = (k==0) ? ic[2] : (k==1) ? ic[3] : (k==2) ? icn[0] : icn[1];
        Gb[(k+2)&3] = pG[(size_t)pidx * H];
      }

      const float tcur = tc[k];
      const float dtv = fmaxf(tcur - prev, 0.f); prev = tcur;

      // consume previous step's broadcast HERE (lgkmcnt wait lands at this use,
      // overlapped with the prefetch/dt work above and the loop backedge)
      f32x2 hp[NP];
      hp[0].x=h03.x; hp[0].y=h03.y; hp[1].x=h03.z; hp[1].y=h03.w;
      hp[2].x=h47.x; hp[2].y=h47.y; hp[3].x=h47.z; hp[3].y=h47.w;
      if constexpr (H == 9){
        hp[4].x = h8p.x; hp[4].y = h8p.y;           // pad zeroed, weight 0
      } else {
        hp[4].x=h8b.x; hp[4].y=h8b.y; hp[5].x=h8b.z; hp[5].y=h8b.w;
      }

      f32x2 aR, aZ, aN;
      aR.x = fmaf(Wrd, dtv, g4.x); aR.y = 0.f;
      aZ.x = fmaf(Wzd, dtv, g4.y); aZ.y = 0.f;
      aN.x = bhn;                  aN.y = 0.f;
#pragma unroll
      for (int j = 0; j < NP; j++){
        aR = __builtin_elementwise_fma(Urp[j], hp[j], aR);
        aZ = __builtin_elementwise_fma(Uzp[j], hp[j], aZ);
        aN = __builtin_elementwise_fma(Unp[j], hp[j], aN);
      }
      const float ar = aR.x + aR.y;        // -log2e * pre_r
      const float az = aZ.x + aZ.y;        // -log2e * pre_z
      const float hn = aN.x + aN.y;        // 2*log2e * (Un·h + bhn)
      const float an = fmaf(Wnd, dtv, g4.z);

      // independent sigmoids (no shared-rcp cross-coupling)
      const float r = frcp(1.f + fexp2(ar));
      const float z = frcp(1.f + fexp2(az));
      const float ec = fexp2(fmaf(r, hn, an));
      const float n  = fmaf(-2.f, frcp(1.f + ec), 1.f);
      hmine = fmaf(z, hmine - n, n);       // (1-z)*n + z*h

      // publish + ISSUE reads now; consumption deferred to next step's top
      hbuf[gb + li] = hmine;
      __builtin_amdgcn_wave_barrier();
      asm volatile("" ::: "memory");       // in-order DS pipe: write lands before reads

      h03 = *reinterpret_cast<const float4*>(&hbuf[gb]);
      h47 = *reinterpret_cast<const float4*>(&hbuf[gb+4]);
      if constexpr (H == 9){
        h8p = *reinterpret_cast<const float2*>(&hbuf[gb+8]);   // [gb+9] pad = 0
      } else {
        h8b = *reinterpret_cast<const float4*>(&hbuf[gb+8]);   // [gb+11] pad = 0
      }
    }
#pragma unroll
    for (int k2 = 0; k2 < 4; k2++){ ic[k2] = icn[k2]; tc[k2] = tcn[k2]; }
  }

  // final h is in the loop-carried temps; one atomic per sequence
  if (li == 0){
    float hv[2*NP];
    hv[0]=h03.x; hv[1]=h03.y; hv[2]=h03.z; hv[3]=h03.w;
    hv[4]=h47.x; hv[5]=h47.y; hv[6]=h47.z; hv[7]=h47.w;
    if constexpr (H == 9){ hv[8]=h8p.x; hv[9]=h8p.y; }
    else { hv[8]=h8b.x; hv[9]=h8b.y; hv[10]=h8b.z; hv[11]=h8b.w; }
    float dot = 0.f;
#pragma unroll
    for (int q = 0; q < H; q++) dot = fmaf(fc_w[dir*H + q], hv[q], dot);
    atomicAdd(out + b, fc_all_w[tail_idx] * dot);
  }
}

__global__ __launch_bounds__(256) void gru_fused(
    const int* __restrict__ dp,  const float* __restrict__ dp_t,
    const int* __restrict__ cp,  const float* __restrict__ cp_t,
    const float4* __restrict__ Gdp, const float4* __restrict__ Gcp,
    const float* __restrict__ Wih_dpf, const float* __restrict__ Whh_dpf, const float* __restrict__ bhh_dpf,
    const float* __restrict__ Wih_dpb, const float* __restrict__ Whh_dpb, const float* __restrict__ bhh_dpb,
    const float* __restrict__ Wih_cpf, const float* __restrict__ Whh_cpf, const float* __restrict__ bhh_cpf,
    const float* __restrict__ Wih_cpb, const float* __restrict__ Whh_cpb, const float* __restrict__ bhh_cpb,
    const float* __restrict__ fc_dp_w, const float* __restrict__ fc_cp_w, const float* __restrict__ fc_all_w,
    float* __restrict__ out, int DP_BLOCKS)
{
  __shared__ __align__(16) float hbuf[28 * 20];
  if ((int)blockIdx.x < DP_BLOCKS){
    gru_body<9, 7, 4096>(blockIdx.x, dp, dp_t, Gdp,
        Wih_dpf, Whh_dpf, bhh_dpf, Wih_dpb, Whh_dpb, bhh_dpb,
        fc_dp_w, fc_all_w, 20, out, hbuf);
  } else {
    gru_body<11, 5, 10000>(blockIdx.x - DP_BLOCKS, cp, cp_t, Gcp,
        Wih_cpf, Whh_cpf, bhh_cpf, Wih_cpb, Whh_cpb, bhh_cpb,
        fc_cp_w, fc_all_w, 21, out, hbuf);
  }
}

extern "C" void kernel_launch(void* const* d_in, const int* in_sizes, int n_in,
                              void* d_out, int out_size, void* d_ws, size_t ws_size,
                              hipStream_t stream)
{
  const float* stat   = (const float*)d_in[0];
  const int*   dp     = (const int*)  d_in[1];
  const int*   cp     = (const int*)  d_in[2];
  const float* dp_t   = (const float*)d_in[3];
  const float* cp_t   = (const float*)d_in[4];
  const float* emb_dp = (const float*)d_in[5];
  const float* emb_cp = (const float*)d_in[6];

  const float* Wih_dpf = (const float*)d_in[7];
  const float* Whh_dpf = (const float*)d_in[8];
  const float* bih_dpf = (const float*)d_in[9];
  const float* bhh_dpf = (const float*)d_in[10];
  const float* Wih_dpb = (const float*)d_in[11];
  const float* Whh_dpb = (const float*)d_in[12];
  const float* bih_dpb = (const float*)d_in[13];
  const float* bhh_dpb = (const float*)d_in[14];
  const float* Wih_cpf = (const float*)d_in[15];
  const float* Whh_cpf = (const float*)d_in[16];
  const float* bih_cpf = (const float*)d_in[17];
  const float* bhh_cpf = (const float*)d_in[18];
  const float* Wih_cpb = (const float*)d_in[19];
  const float* Whh_cpb = (const float*)d_in[20];
  const float* bih_cpb = (const float*)d_in[21];
  const float* bhh_cpb = (const float*)d_in[22];

  const float* fc_dp_w  = (const float*)d_in[23];
  const float* fc_dp_b  = (const float*)d_in[24];
  const float* fc_cp_w  = (const float*)d_in[25];
  const float* fc_cp_b  = (const float*)d_in[26];
  const float* fc_all_w = (const float*)d_in[27];
  const float* fc_all_b = (const float*)d_in[28];

  float* out = (float*)d_out;

  // workspace: dp table (2*4096*9 float4 = 1.18 MB), cp table (2*10000*11 float4 = 3.52 MB)
  float4* Gdp = (float4*)d_ws;
  float4* Gcp = (float4*)((char*)d_ws + (size_t)(2*4096*9) * sizeof(float4));

  {
    const int total = 2*4096*9 + 2*10000*11 + 4096;
    const int blocks = (total + 255) / 256;
    pre_kernel<<<blocks, 256, 0, stream>>>(
        emb_dp, emb_cp,
        Wih_dpf, bih_dpf, bhh_dpf, Wih_dpb, bih_dpb, bhh_dpb,
        Wih_cpf, bih_cpf, bhh_cpf, Wih_cpb, bih_cpb, bhh_cpb,
        stat, fc_all_w, fc_all_b, fc_dp_b, fc_cp_b,
        Gdp, Gcp, out);
  }

  {
    const int DP_BLOCKS = (8192 + 27) / 28;   // H=9,  7 groups/wave
    const int CP_BLOCKS = (8192 + 19) / 20;   // H=11, 5 groups/wave
    gru_fused<<<DP_BLOCKS + CP_BLOCKS, 256, 0, stream>>>(
        dp, dp_t, cp, cp_t, Gdp, Gcp,
        Wih_dpf, Whh_dpf, bhh_dpf, Wih_dpb, Whh_dpb, bhh_dpb,
        Wih_cpf, Whh_cpf, bhh_cpf, Wih_cpb, Whh_cpb, bhh_cpb,
        fc_dp_w, fc_cp_w, fc_all_w, out, DP_BLOCKS);
  }
}